// Round 3
// baseline (138.616 us; speedup 1.0000x reference)
//
#include <hip/hip_runtime.h>
#include <stdint.h>

#define NGRAPH 512
#define NN 64
#define INCH 256
#define TOPK 20
#define EPR 655360

typedef __attribute__((ext_vector_type(8))) short bf16x8;
typedef __attribute__((ext_vector_type(4))) float f32x4;
typedef __attribute__((ext_vector_type(2))) uint32_t u32x2;

// ---- LDS map (dword offsets), total 9408 dwords = 36.75 KB -> 4 blocks/CU ----
#define XLP   0      // u32 [64 d][34]  bf16-pairs of xl (32 pairs + 2 pad)
#define XRP   2176   // u32 [64 d][34]  bf16-pairs of xr
#define ALF   4352   // f32 [64 i][68]  alpha row-major
#define LISTS 0      // u32 [64 row][65] sorted-16 lists (aliases XLP/XRP)
#define MROW  8704   // f32 [4 seg][64 row] partial max
#define SROW  8960   // f32 [4 seg][64 row] partial sum-exp
#define SLOF  9216   // f32 [64]
#define SROF  9280   // f32 [64]
#define ATTO  9344   // f32 [64]
#define SMEM_DW 9408

static __device__ __forceinline__ uint32_t f2bfbits(float f) {
  uint32_t u = __float_as_uint(f);
  return (u + 0x7FFFu + ((u >> 16) & 1u)) >> 16;     // RNE
}
static __device__ __forceinline__ uint32_t pk2(float a, float b) {
  return f2bfbits(a) | (f2bfbits(b) << 16);
}
static __device__ __forceinline__ float lo16f(uint32_t p) { return __uint_as_float(p << 16); }
static __device__ __forceinline__ float hi16f(uint32_t p) { return __uint_as_float(p & 0xFFFF0000u); }

__global__ __launch_bounds__(256, 4) void gat_fused(
    const float* __restrict__ x,    // [32768,256]
    const float* __restrict__ Wl,   // [64,256]
    const float* __restrict__ blv,  // [64]
    const float* __restrict__ Wr,   // [64,256]
    const float* __restrict__ brv,  // [64]
    const float* __restrict__ att,  // [64]
    float* __restrict__ out)        // f32: [idx_i EPR | idx_j EPR | att EPR]
{
  __shared__ __align__(16) uint32_t smemU[SMEM_DW];
  float* smemF = (float*)smemU;

  const int b    = blockIdx.x;
  const int t    = threadIdx.x;
  const int w    = t >> 6;
  const int lane = t & 63;
  const int quad = lane >> 4;
  const int lo   = lane & 15;
  const int nodeBase = b * NN;

  if (t < 64) smemF[ATTO + t] = att[t];

  // ---------------- phase 1: MFMA GEMM [64x256]@[256x128], W from global ----------
  f32x4 acc[8];
  #pragma unroll
  for (int ct = 0; ct < 8; ++ct) acc[ct] = (f32x4){0.f, 0.f, 0.f, 0.f};

  const int r0 = w * 16;
  #pragma unroll
  for (int ks = 0; ks < 8; ++ks) {
    const int k0 = ks * 32 + quad * 8;
    const float* ap = x + (size_t)(nodeBase + r0 + lo) * INCH + k0;
    float4 a0 = *(const float4*)ap;
    float4 a1 = *(const float4*)(ap + 4);
    uint4 au = { pk2(a0.x, a0.y), pk2(a0.z, a0.w), pk2(a1.x, a1.y), pk2(a1.z, a1.w) };
    bf16x8 afrag = __builtin_bit_cast(bf16x8, au);
    #pragma unroll
    for (int ct = 0; ct < 8; ++ct) {
      const float* wrow = ((ct < 4) ? Wl : Wr) + (size_t)((ct & 3) * 16 + lo) * INCH + k0;
      float4 b0 = *(const float4*)wrow;
      float4 b1 = *(const float4*)(wrow + 4);
      uint4 bu = { pk2(b0.x, b0.y), pk2(b0.z, b0.w), pk2(b1.x, b1.y), pk2(b1.z, b1.w) };
      bf16x8 bfrag = __builtin_bit_cast(bf16x8, bu);
      acc[ct] = __builtin_amdgcn_mfma_f32_16x16x32_bf16(afrag, bfrag, acc[ct], 0, 0, 0);
    }
  }

  // phase 1.5: C/D (col=lo -> d, row=quad*4+r -> node) + bias -> LDS bf16 pairs
  #pragma unroll
  for (int ct = 0; ct < 8; ++ct) {
    const int c = (ct & 3) * 16 + lo;                  // d index 0..63
    const float bias = ((ct < 4) ? blv : brv)[c];
    const int base = ((ct < 4) ? XLP : XRP) + c * 34 + (r0 >> 1) + quad * 2;
    u32x2 v = { pk2(acc[ct][0] + bias, acc[ct][1] + bias),
                pk2(acc[ct][2] + bias, acc[ct][3] + bias) };
    *(u32x2*)&smemU[base] = v;
  }
  __syncthreads();

  // ---------------- Sl/Sr: S*[i] = sum_d att[d] * x*[i][d] -------------------------
  if (t < 128) {
    const int i = t & 63;
    const int base = (t < 64) ? XLP : XRP;
    float s = 0.f;
    #pragma unroll 4
    for (int d = 0; d < 64; ++d) {
      uint32_t p = smemU[base + d * 34 + (i >> 1)];
      float v = (i & 1) ? hi16f(p) : lo16f(p);
      s = fmaf(smemF[ATTO + d], v, s);
    }
    smemF[((t < 64) ? SLOF : SROF) + i] = s;
  }
  __syncthreads();

  // ---------------- phase 2: alpha = 0.6(Sl+Sr) + 0.4*sum_d a_d|xl+xr| -------------
  const int i0 = (t >> 4) * 4;
  const int j0 = (t & 15) * 4;
  float pacc[4][4];
  #pragma unroll
  for (int a = 0; a < 4; ++a)
    #pragma unroll
    for (int c = 0; c < 4; ++c) pacc[a][c] = 0.f;

  #pragma unroll 4
  for (int d = 0; d < 64; ++d) {
    u32x2 pl = *(const u32x2*)&smemU[XLP + d * 34 + (i0 >> 1)];
    u32x2 pr = *(const u32x2*)&smemU[XRP + d * 34 + (j0 >> 1)];
    const float ad = smemF[ATTO + d];
    float xl[4] = { lo16f(pl.x), hi16f(pl.x), lo16f(pl.y), hi16f(pl.y) };
    float xr[4] = { lo16f(pr.x), hi16f(pr.x), lo16f(pr.y), hi16f(pr.y) };
    #pragma unroll
    for (int a = 0; a < 4; ++a) {
      #pragma unroll
      for (int c = 0; c < 4; ++c) {
        float s = xl[a] + xr[c];
        pacc[a][c] = fmaf(ad, fabsf(s), pacc[a][c]);
      }
    }
  }
  {
    f32x4 srv = *(const f32x4*)&smemF[SROF + j0];
    #pragma unroll
    for (int a = 0; a < 4; ++a) {
      const float sl = smemF[SLOF + i0 + a];
      f32x4 v;
      #pragma unroll
      for (int c = 0; c < 4; ++c)
        v[c] = 0.6f * (sl + srv[c]) + 0.4f * pacc[a][c];
      *(f32x4*)&smemF[ALF + (i0 + a) * 68 + j0] = v;
    }
  }
  __syncthreads();

  // ---------------- phase 3a: parallel scan — 4 threads per row --------------------
  // thread t: row = t&63, seg = t>>6 scans 16 columns; sorted-16 keys + (max, sumexp)
  {
    const int row = t & 63;
    const int seg = t >> 6;
    const int segBase = seg * 16;
    float fr[16];
    *(f32x4*)&fr[0]  = *(const f32x4*)&smemF[ALF + row * 68 + segBase];
    *(f32x4*)&fr[4]  = *(const f32x4*)&smemF[ALF + row * 68 + segBase + 4];
    *(f32x4*)&fr[8]  = *(const f32x4*)&smemF[ALF + row * 68 + segBase + 8];
    *(f32x4*)&fr[12] = *(const f32x4*)&smemF[ALF + row * 68 + segBase + 12];

    float mp = fr[0];
    #pragma unroll
    for (int e = 1; e < 16; ++e) mp = fmaxf(mp, fr[e]);
    float sp = 0.f;
    #pragma unroll
    for (int e = 0; e < 16; ++e) sp += __expf(fr[e] - mp);

    uint32_t tk[16];
    #pragma unroll
    for (int k = 0; k < 16; ++k) tk[k] = 0u;
    #pragma unroll
    for (int e = 0; e < 16; ++e) {
      const int j = segBase + e;
      uint32_t u = __float_as_uint(fr[e]);
      uint32_t key = u ^ ((uint32_t)((int32_t)u >> 31) | 0x80000000u);  // order-preserving map
      key = (key & 0xFFFFFFC0u) | (uint32_t)(63 - j);                   // index tie-break
      key = (j == row) ? 0u : key;                                      // exclude diagonal
      #pragma unroll
      for (int k = 15; k >= 1; --k)
        tk[k] = (key > tk[k]) ? ((key < tk[k - 1]) ? key : tk[k - 1]) : tk[k];
      tk[0] = (key > tk[0]) ? key : tk[0];
    }
    #pragma unroll
    for (int k = 0; k < 16; ++k)
      smemU[LISTS + row * 65 + segBase + k] = tk[k];
    smemF[MROW + seg * 64 + row] = mp;
    smemF[SROW + seg * 64 + row] = sp;
  }
  __syncthreads();

  // ---------------- phase 3b: 4-way merge-pop top-20 + softmax + store -------------
  if (t < 64) {
    const int row = t;
    const int lb = LISTS + row * 65;
    float m01 = fmaxf(smemF[MROW + row], smemF[MROW + 64 + row]);
    float m23 = fmaxf(smemF[MROW + 128 + row], smemF[MROW + 192 + row]);
    float m = fmaxf(m01, m23);
    float S = 0.f;
    #pragma unroll
    for (int p = 0; p < 4; ++p)
      S += smemF[SROW + p * 64 + row] * __expf(smemF[MROW + p * 64 + row] - m);
    const float invS = 1.0f / S;

    uint32_t h0 = smemU[lb + 0], h1 = smemU[lb + 16], h2 = smemU[lb + 32], h3 = smemU[lb + 48];
    int p0 = 0, p1 = 0, p2 = 0, p3 = 0;
    float va[TOPK], vj[TOPK];

    #pragma unroll
    for (int k = 0; k < TOPK; ++k) {
      uint32_t k01 = (h0 > h1) ? h0 : h1;
      uint32_t k23 = (h2 > h3) ? h2 : h3;
      uint32_t key = (k01 > k23) ? k01 : k23;
      const int wsel = (key == h0) ? 0 : (key == h1) ? 1 : (key == h2) ? 2 : 3;

      uint32_t ub = (key & 0x80000000u) ? (key ^ 0x80000000u) : ~key;
      float alpha = __uint_as_float(ub & 0xFFFFFFC0u);
      const int j = 63 - (int)(key & 63u);
      va[k] = __expf(alpha - m) * invS;
      vj[k] = (float)(nodeBase + j);

      int np = ((wsel == 0) ? p0 : (wsel == 1) ? p1 : (wsel == 2) ? p2 : p3) + 1;
      uint32_t hn = (np < 16) ? smemU[lb + wsel * 16 + np] : 0u;
      p0 += (wsel == 0); p1 += (wsel == 1); p2 += (wsel == 2); p3 += (wsel == 3);
      h0 = (wsel == 0) ? hn : h0;
      h1 = (wsel == 1) ? hn : h1;
      h2 = (wsel == 2) ? hn : h2;
      h3 = (wsel == 3) ? hn : h3;
    }

    const int g = nodeBase + row;
    const float vi = (float)g;
    float4* o0 = (float4*)(out + (size_t)g * 20);
    float4* o1 = (float4*)(out + EPR + (size_t)g * 20);
    float4* o2 = (float4*)(out + 2 * (size_t)EPR + (size_t)g * 20);
    const float4 vi4 = { vi, vi, vi, vi };
    #pragma unroll
    for (int kk = 0; kk < 5; ++kk) {
      o0[kk] = vi4;
      o1[kk] = (float4){ vj[4 * kk], vj[4 * kk + 1], vj[4 * kk + 2], vj[4 * kk + 3] };
      o2[kk] = (float4){ va[4 * kk], va[4 * kk + 1], va[4 * kk + 2], va[4 * kk + 3] };
    }
  }
}

extern "C" void kernel_launch(void* const* d_in, const int* in_sizes, int n_in,
                              void* d_out, int out_size, void* d_ws, size_t ws_size,
                              hipStream_t stream) {
  const float* x   = (const float*)d_in[0];
  // d_in[1] = edge_index, d_in[2] = batch: fully-connected structure is implicit
  const float* Wl  = (const float*)d_in[3];
  const float* bl  = (const float*)d_in[4];
  const float* Wr  = (const float*)d_in[5];
  const float* br  = (const float*)d_in[6];
  const float* att = (const float*)d_in[7];
  gat_fused<<<dim3(NGRAPH), dim3(256), 0, stream>>>(x, Wl, bl, Wr, br, att, (float*)d_out);
}

// Round 4
// 129.714 us; speedup vs baseline: 1.0686x; 1.0686x over previous
//
#include <hip/hip_runtime.h>
#include <stdint.h>

#define NGRAPH 512
#define NN 64
#define INCH 256
#define TOPK 20
#define EPR 655360

typedef __attribute__((ext_vector_type(8))) short bf16x8;
typedef __attribute__((ext_vector_type(4))) float f32x4;

// ---- LDS map (dword offsets), 14272 dwords = 55.75 KB -> 2 blocks/CU (grid-matched)
#define XLF   0      // f32 [64 d][68]  xl transposed (d-major)
#define XRF   4352   // f32 [64 d][68]
#define ALF   8704   // f32 [64 i][68]  alpha row-major
#define LISTS 0      // u32 [64 row][65] sorted-8 lists (aliases XLF; 4160 <= 4352)
#define MROW  13056  // f32 [8 seg][64 row]
#define SROW  13568  // f32 [8 seg][64 row]
#define SLOF  14080  // f32 [64]
#define SROF  14144  // f32 [64]
#define ATTO  14208  // f32 [64]
#define SMEM_DW 14272

static __device__ __forceinline__ uint32_t f2bfbits(float f) {
  uint32_t u = __float_as_uint(f);
  return (u + 0x7FFFu + ((u >> 16) & 1u)) >> 16;     // RNE
}
static __device__ __forceinline__ uint32_t pk2(float a, float b) {
  return f2bfbits(a) | (f2bfbits(b) << 16);
}

// ---- pre-kernel: Wl||Wr (f32) -> bf16 pairs in ws (64 KB), once per launch ----
__global__ __launch_bounds__(256) void wpack(const float* __restrict__ Wl,
                                             const float* __restrict__ Wr,
                                             uint32_t* __restrict__ ws) {
  const int t = blockIdx.x * 256 + threadIdx.x;      // 0..16383 (pair index)
  const float* src = (t < 8192) ? Wl : Wr;
  const int p = t & 8191;
  float2 v = *(const float2*)(src + (size_t)p * 2);
  ws[t] = pk2(v.x, v.y);
}

__global__ __launch_bounds__(512, 4) void gat_fused(
    const float* __restrict__ x,    // [32768,256]
    const uint32_t* __restrict__ ws,// bf16-packed W: [half][64 row][128 pairs]
    const float* __restrict__ blv,  // [64]
    const float* __restrict__ brv,  // [64]
    const float* __restrict__ att,  // [64]
    float* __restrict__ out)        // f32: [idx_i EPR | idx_j EPR | att EPR]
{
  __shared__ __align__(16) uint32_t smemU[SMEM_DW];
  float* smemF = (float*)smemU;

  const int b    = blockIdx.x;
  const int t    = threadIdx.x;
  const int w    = t >> 6;              // wave 0..7
  const int lane = t & 63;
  const int quad = lane >> 4;
  const int lo   = lane & 15;
  const int nodeBase = b * NN;

  if (t < 64) smemF[ATTO + t] = att[t];

  // ---------------- phase 1: MFMA GEMM [64x256]@[256x128] ----------------
  // wave w: half = w>>2 (0->Wl, 1->Wr), rows r0..r0+15, 4 col-tiles of 16
  const int half = w >> 2;
  const int r0   = (w & 3) * 16;
  f32x4 acc[4];
  #pragma unroll
  for (int ct = 0; ct < 4; ++ct) acc[ct] = (f32x4){0.f, 0.f, 0.f, 0.f};

  const uint4* wsV = (const uint4*)ws;
  #pragma unroll
  for (int ks = 0; ks < 8; ++ks) {
    const int k0 = ks * 32 + quad * 8;
    const float* ap = x + (size_t)(nodeBase + r0 + lo) * INCH + k0;
    float4 a0 = *(const float4*)ap;
    float4 a1 = *(const float4*)(ap + 4);
    uint4 au = { pk2(a0.x, a0.y), pk2(a0.z, a0.w), pk2(a1.x, a1.y), pk2(a1.z, a1.w) };
    bf16x8 afrag = __builtin_bit_cast(bf16x8, au);
    #pragma unroll
    for (int ct = 0; ct < 4; ++ct) {
      const int n = ct * 16 + lo;                    // W row = output col d
      uint4 bu = wsV[half * 2048 + n * 32 + ks * 4 + quad];
      bf16x8 bfrag = __builtin_bit_cast(bf16x8, bu);
      acc[ct] = __builtin_amdgcn_mfma_f32_16x16x32_bf16(afrag, bfrag, acc[ct], 0, 0, 0);
    }
  }

  // phase 1.5: C/D (col=lo -> d, row=quad*4+r -> node) + bias -> LDS fp32 transposed
  {
    const int dstBase = half ? XRF : XLF;
    const float* bias = half ? brv : blv;
    #pragma unroll
    for (int ct = 0; ct < 4; ++ct) {
      const int c = ct * 16 + lo;                    // d index 0..63
      const float bb = bias[c];
      f32x4 v = { acc[ct][0] + bb, acc[ct][1] + bb, acc[ct][2] + bb, acc[ct][3] + bb };
      *(f32x4*)&smemF[dstBase + c * 68 + r0 + quad * 4] = v;
    }
  }
  __syncthreads();

  // ---------------- Sl/Sr: S*[i] = sum_d att[d] * x*[i][d] ----------------
  if (t < 128) {
    const int i = t & 63;
    const int base = (t < 64) ? XLF : XRF;
    float s = 0.f;
    #pragma unroll 8
    for (int d = 0; d < 64; ++d)
      s = fmaf(smemF[ATTO + d], smemF[base + d * 68 + i], s);
    smemF[((t < 64) ? SLOF : SROF) + i] = s;
  }
  __syncthreads();

  // ---------------- phase 2: alpha = 0.6(Sl+Sr) + 0.4*sum_d a_d|xl+xr| ------------
  const int i0 = (t >> 4) * 2;                       // 2 rows per thread
  const int j0 = (t & 15) * 4;                       // 4 cols per thread
  float pacc[2][4];
  #pragma unroll
  for (int a = 0; a < 2; ++a)
    #pragma unroll
    for (int c = 0; c < 4; ++c) pacc[a][c] = 0.f;

  #pragma unroll 4
  for (int d = 0; d < 64; ++d) {
    float xl0 = smemF[XLF + d * 68 + i0];
    float xl1 = smemF[XLF + d * 68 + i0 + 1];
    f32x4 xr  = *(const f32x4*)&smemF[XRF + d * 68 + j0];
    const float ad = smemF[ATTO + d];
    #pragma unroll
    for (int c = 0; c < 4; ++c) {
      float s0 = xl0 + xr[c];
      float s1 = xl1 + xr[c];
      pacc[0][c] = fmaf(ad, fabsf(s0), pacc[0][c]);
      pacc[1][c] = fmaf(ad, fabsf(s1), pacc[1][c]);
    }
  }
  {
    f32x4 srv = *(const f32x4*)&smemF[SROF + j0];
    #pragma unroll
    for (int a = 0; a < 2; ++a) {
      const float sl = smemF[SLOF + i0 + a];
      f32x4 v;
      #pragma unroll
      for (int c = 0; c < 4; ++c)
        v[c] = 0.6f * (sl + srv[c]) + 0.4f * pacc[a][c];
      *(f32x4*)&smemF[ALF + (i0 + a) * 68 + j0] = v;
    }
  }
  __syncthreads();

  // ---------------- phase 3a: parallel scan — 8 threads per row -------------------
  {
    const int row = t & 63;
    const int seg = t >> 6;                          // 0..7, 8 cols each
    const int cb  = seg * 8;
    f32x4 f0 = *(const f32x4*)&smemF[ALF + row * 68 + cb];
    f32x4 f1 = *(const f32x4*)&smemF[ALF + row * 68 + cb + 4];
    float fr[8] = { f0[0], f0[1], f0[2], f0[3], f1[0], f1[1], f1[2], f1[3] };

    float mp = fr[0];
    #pragma unroll
    for (int e = 1; e < 8; ++e) mp = fmaxf(mp, fr[e]);
    float sp = 0.f;
    #pragma unroll
    for (int e = 0; e < 8; ++e) sp += __expf(fr[e] - mp);

    uint32_t tk[8];
    #pragma unroll
    for (int k = 0; k < 8; ++k) tk[k] = 0u;
    #pragma unroll
    for (int e = 0; e < 8; ++e) {
      const int j = cb + e;
      uint32_t u = __float_as_uint(fr[e]);
      uint32_t key = u ^ ((uint32_t)((int32_t)u >> 31) | 0x80000000u); // order-preserving
      key = (key & 0xFFFFFFC0u) | (uint32_t)(63 - j);                  // asc-index tie-break
      key = (j == row) ? 0u : key;                                     // exclude diagonal
      #pragma unroll
      for (int k = 7; k >= 1; --k)
        tk[k] = (key > tk[k]) ? ((key < tk[k - 1]) ? key : tk[k - 1]) : tk[k];
      tk[0] = (key > tk[0]) ? key : tk[0];
    }
    #pragma unroll
    for (int k = 0; k < 8; ++k)
      smemU[LISTS + row * 65 + cb + k] = tk[k];
    smemF[MROW + seg * 64 + row] = mp;
    smemF[SROW + seg * 64 + row] = sp;
  }
  __syncthreads();

  // ---------------- phase 3b: 8-way merge-pop top-20 + softmax + store ------------
  if (t < 64) {
    const int row = t;
    const int lb = LISTS + row * 65;
    float m = smemF[MROW + row];
    #pragma unroll
    for (int p = 1; p < 8; ++p) m = fmaxf(m, smemF[MROW + p * 64 + row]);
    float S = 0.f;
    #pragma unroll
    for (int p = 0; p < 8; ++p)
      S += smemF[SROW + p * 64 + row] * __expf(smemF[MROW + p * 64 + row] - m);
    const float invS = 1.0f / S;

    uint32_t h0 = smemU[lb + 0],  h1 = smemU[lb + 8],  h2 = smemU[lb + 16], h3 = smemU[lb + 24];
    uint32_t h4 = smemU[lb + 32], h5 = smemU[lb + 40], h6 = smemU[lb + 48], h7 = smemU[lb + 56];
    int p0 = 0, p1 = 0, p2 = 0, p3 = 0, p4 = 0, p5 = 0, p6 = 0, p7 = 0;
    float va[TOPK], vj[TOPK];

    #pragma unroll
    for (int k = 0; k < TOPK; ++k) {
      uint32_t m01 = (h0 > h1) ? h0 : h1;
      uint32_t m23 = (h2 > h3) ? h2 : h3;
      uint32_t m45 = (h4 > h5) ? h4 : h5;
      uint32_t m67 = (h6 > h7) ? h6 : h7;
      uint32_t ma = (m01 > m23) ? m01 : m23;
      uint32_t mb = (m45 > m67) ? m45 : m67;
      uint32_t key = (ma > mb) ? ma : mb;
      const int wsel = (key == h0) ? 0 : (key == h1) ? 1 : (key == h2) ? 2 :
                       (key == h3) ? 3 : (key == h4) ? 4 : (key == h5) ? 5 :
                       (key == h6) ? 6 : 7;

      uint32_t ub = (key & 0x80000000u) ? (key ^ 0x80000000u) : ~key;
      float alpha = __uint_as_float(ub & 0xFFFFFFC0u);
      const int j = 63 - (int)(key & 63u);
      va[k] = __expf(alpha - m) * invS;
      vj[k] = (float)(nodeBase + j);

      int np = ((wsel == 0) ? p0 : (wsel == 1) ? p1 : (wsel == 2) ? p2 : (wsel == 3) ? p3 :
                (wsel == 4) ? p4 : (wsel == 5) ? p5 : (wsel == 6) ? p6 : p7) + 1;
      uint32_t hn = (np < 8) ? smemU[lb + wsel * 8 + np] : 0u;
      p0 += (wsel == 0); p1 += (wsel == 1); p2 += (wsel == 2); p3 += (wsel == 3);
      p4 += (wsel == 4); p5 += (wsel == 5); p6 += (wsel == 6); p7 += (wsel == 7);
      h0 = (wsel == 0) ? hn : h0;  h1 = (wsel == 1) ? hn : h1;
      h2 = (wsel == 2) ? hn : h2;  h3 = (wsel == 3) ? hn : h3;
      h4 = (wsel == 4) ? hn : h4;  h5 = (wsel == 5) ? hn : h5;
      h6 = (wsel == 6) ? hn : h6;  h7 = (wsel == 7) ? hn : h7;
    }

    const int g = nodeBase + row;
    const float vi = (float)g;
    float4* o0 = (float4*)(out + (size_t)g * 20);
    float4* o1 = (float4*)(out + EPR + (size_t)g * 20);
    float4* o2 = (float4*)(out + 2 * (size_t)EPR + (size_t)g * 20);
    const float4 vi4 = { vi, vi, vi, vi };
    #pragma unroll
    for (int kk = 0; kk < 5; ++kk) {
      o0[kk] = vi4;
      o1[kk] = (float4){ vj[4 * kk], vj[4 * kk + 1], vj[4 * kk + 2], vj[4 * kk + 3] };
      o2[kk] = (float4){ va[4 * kk], va[4 * kk + 1], va[4 * kk + 2], va[4 * kk + 3] };
    }
  }
}

extern "C" void kernel_launch(void* const* d_in, const int* in_sizes, int n_in,
                              void* d_out, int out_size, void* d_ws, size_t ws_size,
                              hipStream_t stream) {
  const float* x   = (const float*)d_in[0];
  // d_in[1] = edge_index, d_in[2] = batch: fully-connected structure is implicit
  const float* Wl  = (const float*)d_in[3];
  const float* bl  = (const float*)d_in[4];
  const float* Wr  = (const float*)d_in[5];
  const float* br  = (const float*)d_in[6];
  const float* att = (const float*)d_in[7];
  uint32_t* wsW = (uint32_t*)d_ws;                   // 64 KB: bf16-packed Wl||Wr

  wpack<<<dim3(64), dim3(256), 0, stream>>>(Wl, Wr, wsW);
  gat_fused<<<dim3(NGRAPH), dim3(512), 0, stream>>>(x, wsW, bl, br, att, (float*)d_out);
}